// Round 6
// baseline (186.584 us; speedup 1.0000x reference)
//
#include <hip/hip_runtime.h>
#include <math.h>

#define N_RAYS 65536
#define LAMBDA_OPACITY 0.001f
#define LAMBDA_DISTORTION 0.001f

#define WAVES_PER_BLOCK 4
#define RAYS_PER_WAVE 8
#define RAYS_PER_BLOCK (WAVES_PER_BLOCK * RAYS_PER_WAVE)   // 32

// ---------------------------------------------------------------------------
// DPP wave64 inclusive-add scan (canonical gfx9 sequence, all-VALU) —
// verified in R5.
// ---------------------------------------------------------------------------
template <int CTRL, int ROW_MASK>
__device__ __forceinline__ float dpp_add(float x) {
    int s = __builtin_amdgcn_update_dpp(0, __float_as_int(x),
                                        CTRL, ROW_MASK, 0xf, false);
    return x + __int_as_float(s);
}

__device__ __forceinline__ float wave64_incl_scan(float x) {
    x = dpp_add<0x111, 0xf>(x);  // row_shr:1
    x = dpp_add<0x112, 0xf>(x);  // row_shr:2
    x = dpp_add<0x114, 0xf>(x);  // row_shr:4
    x = dpp_add<0x118, 0xf>(x);  // row_shr:8
    x = dpp_add<0x142, 0xa>(x);  // row_bcast:15 -> rows 1,3
    x = dpp_add<0x143, 0xc>(x);  // row_bcast:31 -> rows 2,3
    return x;
}

// ---------------------------------------------------------------------------
// Distortion: one wave per 8 consecutive rays, software-pipelined.
// Lanes 0..47 each own one float4 quad of the current ray; ray i+1's three
// 768B loads are issued BEFORE computing ray i (register double buffer), so
// each wave keeps loads in flight continuously instead of one cold round
// trip per wave. Block metadata staged in LDS once (kills meta->data
// serialization). Scan datapath identical to R5 (verified).
// ---------------------------------------------------------------------------
__global__ __launch_bounds__(256)
void distortion_kernel(
    const float* __restrict__ ws,
    const float* __restrict__ deltas,
    const float* __restrict__ ts,
    const int*   __restrict__ rays_a,
    float* __restrict__ out)
{
    __shared__ int smeta[RAYS_PER_BLOCK * 3];

    const int lane = threadIdx.x & 63;
    const int wave = threadIdx.x >> 6;

    if (threadIdx.x < RAYS_PER_BLOCK * 3)
        smeta[threadIdx.x] = rays_a[blockIdx.x * (RAYS_PER_BLOCK * 3) + threadIdx.x];
    __syncthreads();

    const int m0 = wave * (RAYS_PER_WAVE * 3);

    // all meta into registers up-front (independent ds_reads, one-time cost)
    int r_st[RAYS_PER_WAVE], r_ct[RAYS_PER_WAVE];
    #pragma unroll
    for (int i = 0; i < RAYS_PER_WAVE; ++i) {
        r_st[i] = smeta[m0 + 3 * i + 1];
        r_ct[i] = smeta[m0 + 3 * i + 2];
    }

    float4 vw, vt, vd;
    // prologue: issue ray 0's loads
    {
        const bool fastp = (r_ct[0] == 192) && ((r_st[0] & 3) == 0);
        if (fastp && lane < 48) {
            vw = *(const float4*)(ws     + r_st[0] + 4 * lane);
            vt = *(const float4*)(ts     + r_st[0] + 4 * lane);
            vd = *(const float4*)(deltas + r_st[0] + 4 * lane);
        }
        __builtin_amdgcn_sched_barrier(0);
    }

    #pragma unroll
    for (int i = 0; i < RAYS_PER_WAVE; ++i) {
        const bool fastp = (r_ct[i] == 192) && ((r_st[i] & 3) == 0);

        // ---- prefetch ray i+1 before touching ray i's data ----
        float4 nw, nt, nd;
        if (i + 1 < RAYS_PER_WAVE) {
            const bool fastn = (r_ct[i + 1] == 192) && ((r_st[i + 1] & 3) == 0);
            if (fastn && lane < 48) {
                nw = *(const float4*)(ws     + r_st[i + 1] + 4 * lane);
                nt = *(const float4*)(ts     + r_st[i + 1] + 4 * lane);
                nd = *(const float4*)(deltas + r_st[i + 1] + 4 * lane);
            }
            __builtin_amdgcn_sched_barrier(0);
        }

        // ---- unpack current ray (first use -> waitcnt leaves prefetch in flight) ----
        float w[4] = {0.f, 0.f, 0.f, 0.f};
        float t[4] = {0.f, 0.f, 0.f, 0.f};
        float d[4] = {0.f, 0.f, 0.f, 0.f};
        if (fastp) {
            if (lane < 48) {
                w[0]=vw.x; w[1]=vw.y; w[2]=vw.z; w[3]=vw.w;
                t[0]=vt.x; t[1]=vt.y; t[2]=vt.z; t[3]=vt.w;
                d[0]=vd.x; d[1]=vd.y; d[2]=vd.z; d[3]=vd.w;
            }
        } else {
            // generic path (any count, any alignment): guarded scalar loads
            #pragma unroll
            for (int e = 0; e < 4; ++e) {
                const int p  = 4 * lane + e;
                const bool ok = p < r_ct[i];
                w[e] = ok ? ws[r_st[i] + p]     : 0.f;
                t[e] = ok ? ts[r_st[i] + p]     : 0.f;
                d[e] = ok ? deltas[r_st[i] + p] : 0.f;
            }
        }

        // ---- per-lane quad totals ----
        const float wt0 = w[0] * t[0], wt1 = w[1] * t[1];
        const float wt2 = w[2] * t[2], wt3 = w[3] * t[3];
        const float lw  = (w[0] + w[1]) + (w[2] + w[3]);
        const float lwt = (wt0 + wt1) + (wt2 + wt3);

        // ---- DPP inclusive scans over quad totals ----
        const float iw  = wave64_incl_scan(lw);
        const float iwt = wave64_incl_scan(lwt);

        float e_w  = iw  - lw;
        float e_wt = iwt - lwt;

        float acc = 0.f;
        #pragma unroll
        for (int e = 0; e < 4; ++e) {
            acc += 2.f * w[e] * (t[e] * e_w - e_wt) + w[e] * w[e] * d[e] * (1.f / 3.f);
            e_w  += w[e];
            e_wt += w[e] * t[e];
        }

        // ray total via one more DPP scan; lane 63 holds the full sum
        const float tot = wave64_incl_scan(acc);
        if (lane == 63)
            out[3 * N_RAYS + smeta[m0 + 3 * i]] = LAMBDA_DISTORTION * tot;

        // rotate double buffer
        vw = nw; vt = nt; vd = nd;
    }
}

// ---------------------------------------------------------------------------
// Per-ray cheap terms: 1 thread per ray, fully coalesced (~6 MB total).
// ---------------------------------------------------------------------------
__global__ __launch_bounds__(256)
void perray_kernel(
    const float* __restrict__ rgb_coarse,
    const float* __restrict__ rgb_fine,
    const float* __restrict__ rgb_target,
    const float* __restrict__ depth,
    const float* __restrict__ depth_target,
    const float* __restrict__ opacity,
    float* __restrict__ out)
{
    const int r = blockIdx.x * blockDim.x + threadIdx.x;
    if (r >= N_RAYS) return;

    const float rt0 = rgb_target[r * 3 + 0];
    const float rt1 = rgb_target[r * 3 + 1];
    const float rt2 = rgb_target[r * 3 + 2];
    const float c0 = rgb_coarse[r * 3 + 0] - rt0;
    const float c1 = rgb_coarse[r * 3 + 1] - rt1;
    const float c2 = rgb_coarse[r * 3 + 2] - rt2;
    const float f0 = rgb_fine[r * 3 + 0] - rt0;
    const float f1 = rgb_fine[r * 3 + 1] - rt1;
    const float f2 = rgb_fine[r * 3 + 2] - rt2;

    out[r] = (c0 * c0 + c1 * c1 + c2 * c2) * (1.f / 3.f)
           + (f0 * f0 + f1 * f1 + f2 * f2) * (1.f / 3.f);

    out[N_RAYS + r] = fabsf(depth[r] - depth_target[r]);

    const float o = opacity[r] + 1e-10f;
    out[2 * N_RAYS + r] = LAMBDA_OPACITY * (-o * logf(o));
}

extern "C" void kernel_launch(void* const* d_in, const int* in_sizes, int n_in,
                              void* d_out, int out_size, void* d_ws, size_t ws_size,
                              hipStream_t stream) {
    const float* rgb_coarse   = (const float*)d_in[0];
    const float* rgb_fine     = (const float*)d_in[1];
    const float* rgb_target   = (const float*)d_in[2];
    const float* depth        = (const float*)d_in[3];
    const float* depth_target = (const float*)d_in[4];
    const float* opacity      = (const float*)d_in[5];
    const float* ws           = (const float*)d_in[6];
    const float* deltas       = (const float*)d_in[7];
    const float* ts           = (const float*)d_in[8];
    const int*   rays_a       = (const int*)d_in[9];
    float* out = (float*)d_out;

    distortion_kernel<<<N_RAYS / RAYS_PER_BLOCK, 256, 0, stream>>>(
        ws, deltas, ts, rays_a, out);

    perray_kernel<<<N_RAYS / 256, 256, 0, stream>>>(
        rgb_coarse, rgb_fine, rgb_target, depth, depth_target, opacity, out);
}

// Round 7
// 180.406 us; speedup vs baseline: 1.0342x; 1.0342x over previous
//
#include <hip/hip_runtime.h>
#include <math.h>

#define N_RAYS 65536
#define LAMBDA_OPACITY 0.001f
#define LAMBDA_DISTORTION 0.001f

// ---------------------------------------------------------------------------
// DPP wave64 inclusive-add scan (canonical gfx9 sequence, all-VALU) —
// verified in R5.
// ---------------------------------------------------------------------------
template <int CTRL, int ROW_MASK>
__device__ __forceinline__ float dpp_add(float x) {
    int s = __builtin_amdgcn_update_dpp(0, __float_as_int(x),
                                        CTRL, ROW_MASK, 0xf, false);
    return x + __int_as_float(s);
}

__device__ __forceinline__ float wave64_incl_scan(float x) {
    x = dpp_add<0x111, 0xf>(x);  // row_shr:1
    x = dpp_add<0x112, 0xf>(x);  // row_shr:2
    x = dpp_add<0x114, 0xf>(x);  // row_shr:4
    x = dpp_add<0x118, 0xf>(x);  // row_shr:8
    x = dpp_add<0x142, 0xa>(x);  // row_bcast:15 -> rows 1,3
    x = dpp_add<0x143, 0xc>(x);  // row_bcast:31 -> rows 2,3
    return x;
}

// ---------------------------------------------------------------------------
// Distortion: one 64-lane wave per ray (R5 structure). NEW in R7: the three
// 768B data loads are issued SPECULATIVELY from the identity-layout address
// (start = 192*ray) concurrently with the rays_a meta load, collapsing the
// wave's two serialized memory round trips (meta -> data) into one. The
// loaded meta is then checked; mismatch falls back to generic guarded loads.
// Speculative addresses are always in-bounds: 192*ray + 192 <= N_RAYS*192.
// ---------------------------------------------------------------------------
__global__ __launch_bounds__(256)
void distortion_kernel(
    const float* __restrict__ ws,
    const float* __restrict__ deltas,
    const float* __restrict__ ts,
    const int*   __restrict__ rays_a,
    float* __restrict__ out)
{
    const int lane = threadIdx.x & 63;
    const int ray  = blockIdx.x * 4 + (threadIdx.x >> 6);

    // --- speculative data loads (identity layout), issued immediately ---
    float4 vw, vt, vd;
    if (lane < 48) {
        const int sp = 192 * ray + 4 * lane;
        vw = *(const float4*)(ws     + sp);
        vt = *(const float4*)(ts     + sp);
        vd = *(const float4*)(deltas + sp);
    }

    // --- meta load, independent of the data loads -> same round trip ---
    const int out_ray = rays_a[ray * 3 + 0];
    const int start   = rays_a[ray * 3 + 1];
    const int count   = rays_a[ray * 3 + 2];

    // pin: everything above issues before anything below is scheduled, so the
    // speculative loads cannot be sunk into the fast branch (behind the meta
    // wait), which would re-serialize the two round trips.
    __builtin_amdgcn_sched_barrier(0);

    float w[4] = {0.f, 0.f, 0.f, 0.f};
    float t[4] = {0.f, 0.f, 0.f, 0.f};
    float d[4] = {0.f, 0.f, 0.f, 0.f};

    if (start == 192 * ray && count == 192) {
        // speculation correct (always, for this problem's identity layout)
        if (lane < 48) {
            w[0]=vw.x; w[1]=vw.y; w[2]=vw.z; w[3]=vw.w;
            t[0]=vt.x; t[1]=vt.y; t[2]=vt.z; t[3]=vt.w;
            d[0]=vd.x; d[1]=vd.y; d[2]=vd.z; d[3]=vd.w;
        }
    } else {
        // generic fallback: any start/count, guarded scalar loads
        #pragma unroll
        for (int e = 0; e < 4; ++e) {
            const int p  = 4 * lane + e;
            const bool ok = p < count;
            w[e] = ok ? ws[start + p]     : 0.f;
            t[e] = ok ? ts[start + p]     : 0.f;
            d[e] = ok ? deltas[start + p] : 0.f;
        }
    }

    // --- per-lane quad totals ---
    const float wt0 = w[0] * t[0], wt1 = w[1] * t[1];
    const float wt2 = w[2] * t[2], wt3 = w[3] * t[3];
    const float lw  = (w[0] + w[1]) + (w[2] + w[3]);
    const float lwt = (wt0 + wt1) + (wt2 + wt3);

    // --- DPP inclusive scans over quad totals (two independent chains) ---
    const float iw  = wave64_incl_scan(lw);
    const float iwt = wave64_incl_scan(lwt);

    // exclusive base for this quad
    float e_w  = iw  - lw;
    float e_wt = iwt - lwt;

    // lane-local sequential exclusive accumulation over the 4 samples
    float acc = 0.f;
    #pragma unroll
    for (int e = 0; e < 4; ++e) {
        acc += 2.f * w[e] * (t[e] * e_w - e_wt) + w[e] * w[e] * d[e] * (1.f / 3.f);
        e_w  += w[e];
        e_wt += w[e] * t[e];
    }

    // ray total via one more DPP scan; lane 63 holds the full sum
    const float tot = wave64_incl_scan(acc);
    if (lane == 63)
        out[3 * N_RAYS + out_ray] = LAMBDA_DISTORTION * tot;
}

// ---------------------------------------------------------------------------
// Per-ray cheap terms: 1 thread per ray, fully coalesced (~6 MB total).
// ---------------------------------------------------------------------------
__global__ __launch_bounds__(256)
void perray_kernel(
    const float* __restrict__ rgb_coarse,
    const float* __restrict__ rgb_fine,
    const float* __restrict__ rgb_target,
    const float* __restrict__ depth,
    const float* __restrict__ depth_target,
    const float* __restrict__ opacity,
    float* __restrict__ out)
{
    const int r = blockIdx.x * blockDim.x + threadIdx.x;
    if (r >= N_RAYS) return;

    const float rt0 = rgb_target[r * 3 + 0];
    const float rt1 = rgb_target[r * 3 + 1];
    const float rt2 = rgb_target[r * 3 + 2];
    const float c0 = rgb_coarse[r * 3 + 0] - rt0;
    const float c1 = rgb_coarse[r * 3 + 1] - rt1;
    const float c2 = rgb_coarse[r * 3 + 2] - rt2;
    const float f0 = rgb_fine[r * 3 + 0] - rt0;
    const float f1 = rgb_fine[r * 3 + 1] - rt1;
    const float f2 = rgb_fine[r * 3 + 2] - rt2;

    out[r] = (c0 * c0 + c1 * c1 + c2 * c2) * (1.f / 3.f)
           + (f0 * f0 + f1 * f1 + f2 * f2) * (1.f / 3.f);

    out[N_RAYS + r] = fabsf(depth[r] - depth_target[r]);

    const float o = opacity[r] + 1e-10f;
    out[2 * N_RAYS + r] = LAMBDA_OPACITY * (-o * logf(o));
}

extern "C" void kernel_launch(void* const* d_in, const int* in_sizes, int n_in,
                              void* d_out, int out_size, void* d_ws, size_t ws_size,
                              hipStream_t stream) {
    const float* rgb_coarse   = (const float*)d_in[0];
    const float* rgb_fine     = (const float*)d_in[1];
    const float* rgb_target   = (const float*)d_in[2];
    const float* depth        = (const float*)d_in[3];
    const float* depth_target = (const float*)d_in[4];
    const float* opacity      = (const float*)d_in[5];
    const float* ws           = (const float*)d_in[6];
    const float* deltas       = (const float*)d_in[7];
    const float* ts           = (const float*)d_in[8];
    const int*   rays_a       = (const int*)d_in[9];
    float* out = (float*)d_out;

    // 4 waves per block, 1 ray per wave (R5 grid shape)
    distortion_kernel<<<N_RAYS / 4, 256, 0, stream>>>(
        ws, deltas, ts, rays_a, out);

    perray_kernel<<<N_RAYS / 256, 256, 0, stream>>>(
        rgb_coarse, rgb_fine, rgb_target, depth, depth_target, opacity, out);
}